// Round 19
// baseline (105.045 us; speedup 1.0000x reference)
//
#include <hip/hip_runtime.h>

typedef short bf16x8 __attribute__((ext_vector_type(8)));
typedef float f32x4 __attribute__((ext_vector_type(4)));
typedef unsigned short u16;

__device__ __forceinline__ u16 f2bf(float f) {
    unsigned u = __builtin_bit_cast(unsigned, f);
    u += 0x7FFF + ((u >> 16) & 1);
    return (u16)(u >> 16);
}

// Problem dims
constexpr int Hh = 64, Ww = 64, Ci = 128;
constexpr int Fo = 256, OH = 62, OW = 62;
constexpr int Ktot = 3 * 3 * Ci;      // 1152
constexpr int BM = 128, BK = 64;      // half-tap per K-step -> 32 KB LDS, 5 blocks/CU
constexpr int NSTEP = Ktot / BK;      // 18
constexpr int NWG = 1922;             // (123008/128) * 2 col-blocks
constexpr long NEL_IN = 32L * 64 * 64 * 128;        // 16,777,216
constexpr size_t WS_IN_BYTES = (size_t)NEL_IN * 2;  // 33,554,432
constexpr size_t WS_WT_OFF   = WS_IN_BYTES;
constexpr size_t WS_NEED     = WS_IN_BYTES + 294912ull * 2;

#define GLD_LDS(src, dst) __builtin_amdgcn_global_load_lds( \
    (const __attribute__((address_space(1))) unsigned int*)(src), \
    (__attribute__((address_space(3))) unsigned int*)(dst), 16, 0, 0)
#define SB0 __builtin_amdgcn_sched_barrier(0)

// ---- fused pre-pass: input fp32->bf16 (blocks 0..8191), wt transpose (8192..8335) ----
__global__ __launch_bounds__(256) void cvt_all(const float* __restrict__ in,
                                               const float* __restrict__ wt,
                                               u16* __restrict__ inb,
                                               u16* __restrict__ wtb) {
    const int b = blockIdx.x;
    if (b < 8192) {
        const int i = b * 256 + threadIdx.x;
        const float4* s = (const float4*)in + (long)i * 2;
        float4 v0 = s[0], v1 = s[1];
        bf16x8 p;
        p[0] = (short)f2bf(v0.x); p[1] = (short)f2bf(v0.y);
        p[2] = (short)f2bf(v0.z); p[3] = (short)f2bf(v0.w);
        p[4] = (short)f2bf(v1.x); p[5] = (short)f2bf(v1.y);
        p[6] = (short)f2bf(v1.z); p[7] = (short)f2bf(v1.w);
        ((bf16x8*)inb)[i] = p;
    } else {
        // wt [k=1152][f=256] fp32 -> [f=256][k=1152] bf16
        const int t = (b - 8192) * 256 + threadIdx.x;   // 0 .. 36863
        const int f = t / 144, k8 = t % 144;
        bf16x8 p;
        #pragma unroll
        for (int j = 0; j < 8; ++j)
            p[j] = (short)f2bf(wt[(k8 * 8 + j) * Fo + f]);
        ((bf16x8*)wtb)[f * 144 + k8] = p;
    }
}

// ---- main: R4 staging (BK=64, 32KB LDS -> 5 blocks/CU) + R15 SB0 interleave ----
__global__ __launch_bounds__(256) void conv_mfma(
    const u16* __restrict__ inb,   // bf16 [32][64][64][128]
    const u16* __restrict__ wtb,   // bf16 [256][1152]
    float* __restrict__ out)       // [123008][256] fp32, r=(oh*62+ow)*32+b
{
    __shared__ __align__(16) short As[BM * BK];   // 16 KB, 128B rows, swizzled
    __shared__ __align__(16) short Bs[BM * BK];   // 16 KB, 128B rows, swizzled

    const int tid  = threadIdx.x;
    const int lane = tid & 63;
    const int wv   = tid >> 6;
    const int wr   = wv >> 1, wc = wv & 1;

    // bijective XCD swizzle
    constexpr int q = NWG / 8, rr = NWG % 8;
    const int orig = blockIdx.x;
    const int xcd = orig & 7, idx = orig >> 3;
    const int wgid = (xcd < rr ? xcd * (q + 1) : rr * (q + 1) + (xcd - rr) * q) + idx;

    const int colb = wgid & 1;
    const int rowb = wgid >> 1;
    const int r0   = rowb * BM;
    const int f0g  = colb * 128;

    // ---- DMA staging addresses (R4-proven mapping) ----
    // Row = 128 B. Instr j covers rows wv*32+j*8 .. +7; lane l -> row +(l>>3),
    // chunk l&7. Pre-swizzled source chunk (l&7)^(row&7): LDS chunk c of row r
    // holds global chunk c^(r&7); fragment reads apply the same XOR.
    const int lrow8 = lane >> 3;
    const int schunk = ((lane & 7) ^ lrow8) * 16;
    long abyte[4], bbyte[4];
    #pragma unroll
    for (int j = 0; j < 4; ++j) {
        const int r  = r0 + wv * 32 + j * 8 + lrow8;
        const int bb = r & 31;
        const int pix = r >> 5;
        const int ow = pix % OW, oh = pix / OW;
        abyte[j] = (long)(((bb * Hh + oh) * Ww + ow) * Ci) * 2 + schunk;
        const int f = f0g + wv * 32 + j * 8 + lrow8;
        bbyte[j] = (long)f * (Ktot * 2) + schunk;
    }

    auto stage = [&](int step) {
        const int kb = step >> 1, c0 = (step & 1) << 6;
        const int kh = kb / 3, kw = kb % 3;
        const long tap = (long)((kh * Ww + kw) * Ci + c0) * 2;
        const long bof = (long)step * 128;
        #pragma unroll
        for (int j = 0; j < 4; ++j)
            GLD_LDS((const char*)inb + abyte[j] + tap, &As[(wv * 32 + j * 8) * BK]);
        #pragma unroll
        for (int j = 0; j < 4; ++j)
            GLD_LDS((const char*)wtb + bbyte[j] + bof, &Bs[(wv * 32 + j * 8) * BK]);
    };

    f32x4 acc[4][4];
    #pragma unroll
    for (int m = 0; m < 4; ++m)
        #pragma unroll
        for (int n = 0; n < 4; ++n) acc[m][n] = (f32x4){0.f, 0.f, 0.f, 0.f};

    stage(0);

    const int lrow = lane & 15;
    const int lq   = lane >> 4;

    // fragment read for one K=32 substep: 4 A + 4 B ds_read_b128
    auto readfr = [&](int ks, bf16x8 (&a)[4], bf16x8 (&b)[4]) {
        const int off = ks * 64 + lq * 16;       // byte offset within 128B row
        #pragma unroll
        for (int m = 0; m < 4; ++m) {
            const int row = wr * 64 + m * 16 + lrow;
            a[m] = *(const bf16x8*)((const char*)As + row * 128 + (off ^ ((row & 7) << 4)));
        }
        #pragma unroll
        for (int n = 0; n < 4; ++n) {
            const int frow = wc * 64 + n * 16 + lrow;
            b[n] = *(const bf16x8*)((const char*)Bs + frow * 128 + (off ^ ((frow & 7) << 4)));
        }
    };
    auto mfma16 = [&](const bf16x8 (&a)[4], const bf16x8 (&b)[4]) {
        #pragma unroll
        for (int m = 0; m < 4; ++m)
            #pragma unroll
            for (int n = 0; n < 4; ++n)
                acc[m][n] = __builtin_amdgcn_mfma_f32_16x16x32_bf16(a[m], b[n], acc[m][n], 0, 0, 0);
    };

    for (int step = 0; step < NSTEP; ++step) {
        __syncthreads();   // drains DMA: staged tile ready

        // R15 SB0-pinned 2-slot alternation (2 substeps at BK=64)
        bf16x8 a0[4], b0[4], a1[4], b1[4];
        readfr(0, a0, b0);
        readfr(1, a1, b1);
        SB0;
        mfma16(a0, b0);        // waits lgkmcnt(8): ks0 landed, ks1 in flight
        SB0;
        mfma16(a1, b1);

        __syncthreads();   // all waves done reading
        if (step + 1 < NSTEP) stage(step + 1);
    }

    // ---- epilogue: relu + store ----
    const int lcol = lane & 15;
    const int lr4  = (lane >> 4) * 4;
    #pragma unroll
    for (int m = 0; m < 4; ++m) {
        #pragma unroll
        for (int n = 0; n < 4; ++n) {
            const int col = f0g + wc * 64 + n * 16 + lcol;
            const int rowbase = r0 + wr * 64 + m * 16 + lr4;
            #pragma unroll
            for (int e = 0; e < 4; ++e) {
                float v = acc[m][n][e];
                out[(long)(rowbase + e) * Fo + col] = v > 0.f ? v : 0.f;
            }
        }
    }
}

// ================== fallback (round-2 proven kernel, no workspace) ==================
__global__ __launch_bounds__(256) void conv_mfma_fb(
    const float* __restrict__ in, const float* __restrict__ wt,
    float* __restrict__ out)
{
    __shared__ __align__(16) short As[128 * 64];
    __shared__ __align__(16) short Bs[128 * 64];
    const int tid  = threadIdx.x;
    const int lane = tid & 63;
    const int wv   = tid >> 6;
    const int wr   = wv >> 1, wc = wv & 1;
    constexpr int q2 = NWG / 8, rr2 = NWG % 8;
    const int orig = blockIdx.x;
    const int xcd = orig & 7, idx = orig >> 3;
    const int wgid = (xcd < rr2 ? xcd * (q2 + 1) : rr2 * (q2 + 1) + (xcd - rr2) * q2) + idx;
    const int colb = wgid & 1;
    const int rowb = wgid >> 1;
    const int r0   = rowb * 128;
    const int f0g  = colb * 128;
    const int ai = tid >> 1;
    const int ah = tid & 1;
    const int r  = r0 + ai;
    const int bb  = r & 31;
    const int pix = r >> 5;
    const int ow  = pix % OW;
    const int oh  = pix / OW;
    const float* abase = in + ((bb * Hh + oh) * Ww + ow) * Ci;
    const int bk = tid & 63;
    const int bf = (tid >> 6) * 32;
    constexpr int FNSTEP = 18;

    auto loadA = [&](int step, float4 (&pa)[8]) {
        const int kb = step >> 1;
        const int c0 = (step & 1) << 6;
        const int kh = kb / 3, kw = kb % 3;
        const float* src = abase + (kh * Ww + kw) * Ci + c0 + ah * 32;
        #pragma unroll
        for (int c = 0; c < 8; ++c) pa[c] = ((const float4*)src)[c];
    };
    auto writeA = [&](const float4 (&pa)[8]) {
        char* dst = (char*)As + ai * 128;
        const int swz = (ai & 7) << 4;
        #pragma unroll
        for (int c = 0; c < 4; ++c) {
            float4 v0 = pa[2 * c], v1 = pa[2 * c + 1];
            bf16x8 pk;
            pk[0] = (short)f2bf(v0.x); pk[1] = (short)f2bf(v0.y);
            pk[2] = (short)f2bf(v0.z); pk[3] = (short)f2bf(v0.w);
            pk[4] = (short)f2bf(v1.x); pk[5] = (short)f2bf(v1.y);
            pk[6] = (short)f2bf(v1.z); pk[7] = (short)f2bf(v1.w);
            *(bf16x8*)(dst + ((ah * 64 + c * 16) ^ swz)) = pk;
        }
    };
    auto loadB = [&](int step, float4 (&pb)[8]) {
        const float* src = wt + (step * 64 + bk) * Fo + f0g + bf;
        #pragma unroll
        for (int c = 0; c < 8; ++c) pb[c] = ((const float4*)src)[c];
    };
    auto writeB = [&](const float4 (&pb)[8]) {
        const int k2 = bk * 2;
        #pragma unroll
        for (int c = 0; c < 8; ++c) {
            float4 v = pb[c];
            const int fl = bf + c * 4;
            *(u16*)((char*)Bs + (fl + 0) * 128 + (k2 ^ (((fl + 0) & 7) << 4))) = f2bf(v.x);
            *(u16*)((char*)Bs + (fl + 1) * 128 + (k2 ^ (((fl + 1) & 7) << 4))) = f2bf(v.y);
            *(u16*)((char*)Bs + (fl + 2) * 128 + (k2 ^ (((fl + 2) & 7) << 4))) = f2bf(v.z);
            *(u16*)((char*)Bs + (fl + 3) * 128 + (k2 ^ (((fl + 3) & 7) << 4))) = f2bf(v.w);
        }
    };

    f32x4 acc[4][4];
    #pragma unroll
    for (int m = 0; m < 4; ++m)
        #pragma unroll
        for (int n = 0; n < 4; ++n) acc[m][n] = (f32x4){0.f, 0.f, 0.f, 0.f};
    {
        float4 pa[8], pb[8];
        loadA(0, pa); loadB(0, pb);
        writeA(pa); writeB(pb);
    }
    __syncthreads();
    const int lrow = tid & 15;
    const int lq   = (tid & 63) >> 4;
    for (int step = 0; step < FNSTEP; ++step) {
        float4 na[8], nb[8];
        if (step + 1 < FNSTEP) { loadA(step + 1, na); loadB(step + 1, nb); }
        #pragma unroll
        for (int ks = 0; ks < 2; ++ks) {
            bf16x8 a[4], b[4];
            const int off = ks * 64 + lq * 16;
            #pragma unroll
            for (int m = 0; m < 4; ++m) {
                const int row = wr * 64 + m * 16 + lrow;
                a[m] = *(const bf16x8*)((const char*)As + row * 128 + (off ^ ((row & 7) << 4)));
            }
            #pragma unroll
            for (int n = 0; n < 4; ++n) {
                const int row = wc * 64 + n * 16 + lrow;
                b[n] = *(const bf16x8*)((const char*)Bs + row * 128 + (off ^ ((row & 7) << 4)));
            }
            #pragma unroll
            for (int m = 0; m < 4; ++m)
                #pragma unroll
                for (int n = 0; n < 4; ++n)
                    acc[m][n] = __builtin_amdgcn_mfma_f32_16x16x32_bf16(a[m], b[n], acc[m][n], 0, 0, 0);
        }
        __syncthreads();
        if (step + 1 < FNSTEP) { writeA(na); writeB(nb); }
        __syncthreads();
    }
    const int lcol = tid & 15;
    const int lr4  = ((tid & 63) >> 4) * 4;
    #pragma unroll
    for (int m = 0; m < 4; ++m) {
        #pragma unroll
        for (int n = 0; n < 4; ++n) {
            const int col = f0g + wc * 64 + n * 16 + lcol;
            const int rowbase = r0 + wr * 64 + m * 16 + lr4;
            #pragma unroll
            for (int e = 0; e < 4; ++e) {
                float v = acc[m][n][e];
                out[(rowbase + e) * Fo + col] = v > 0.f ? v : 0.f;
            }
        }
    }
}

extern "C" void kernel_launch(void* const* d_in, const int* in_sizes, int n_in,
                              void* d_out, int out_size, void* d_ws, size_t ws_size,
                              hipStream_t stream) {
    const float* in  = (const float*)d_in[0];
    const float* wt  = (const float*)d_in[1];
    float* out = (float*)d_out;
    if (ws_size >= WS_NEED) {
        u16* inb = (u16*)d_ws;
        u16* wtb = (u16*)((char*)d_ws + WS_WT_OFF);
        cvt_all<<<dim3(8336), dim3(256), 0, stream>>>(in, wt, inb, wtb);
        conv_mfma<<<dim3(NWG), dim3(256), 0, stream>>>(inb, wtb, out);
    } else {
        conv_mfma_fb<<<dim3(NWG), dim3(256), 0, stream>>>(in, wt, out);
    }
}

// Round 20
// 95.067 us; speedup vs baseline: 1.1050x; 1.1050x over previous
//
#include <hip/hip_runtime.h>

typedef short bf16x8 __attribute__((ext_vector_type(8)));
typedef float f32x4 __attribute__((ext_vector_type(4)));
typedef unsigned short u16;

__device__ __forceinline__ u16 f2bf(float f) {
    unsigned u = __builtin_bit_cast(unsigned, f);
    u += 0x7FFF + ((u >> 16) & 1);
    return (u16)(u >> 16);
}

// Problem dims
constexpr int Hh = 64, Ww = 64, Ci = 128;
constexpr int Fo = 256, OH = 62, OW = 62;
constexpr int Ktot = 3 * 3 * Ci;      // 1152
constexpr int BM = 128, BK = 128;     // one tap (kh,kw) per K-step
constexpr int NSTEP = 9;              // 9 taps
constexpr int NWG = 1922;             // (123008/128) * 2 col-blocks
constexpr long NEL_IN = 32L * 64 * 64 * 128;        // 16,777,216
constexpr size_t WS_IN_BYTES = (size_t)NEL_IN * 2;  // 33,554,432
constexpr size_t WS_WT_OFF   = WS_IN_BYTES;
constexpr size_t WS_NEED     = WS_IN_BYTES + 294912ull * 2;

#define GLD_LDS(src, dst) __builtin_amdgcn_global_load_lds( \
    (const __attribute__((address_space(1))) unsigned int*)(src), \
    (__attribute__((address_space(3))) unsigned int*)(dst), 16, 0, 0)
#define SB0 __builtin_amdgcn_sched_barrier(0)

// ---- fused pre-pass: input fp32->bf16 (blocks 0..8191), wt transpose (8192..8335) ----
__global__ __launch_bounds__(256) void cvt_all(const float* __restrict__ in,
                                               const float* __restrict__ wt,
                                               u16* __restrict__ inb,
                                               u16* __restrict__ wtb) {
    const int b = blockIdx.x;
    if (b < 8192) {
        const int i = b * 256 + threadIdx.x;
        const float4* s = (const float4*)in + (long)i * 2;
        float4 v0 = s[0], v1 = s[1];
        bf16x8 p;
        p[0] = (short)f2bf(v0.x); p[1] = (short)f2bf(v0.y);
        p[2] = (short)f2bf(v0.z); p[3] = (short)f2bf(v0.w);
        p[4] = (short)f2bf(v1.x); p[5] = (short)f2bf(v1.y);
        p[6] = (short)f2bf(v1.z); p[7] = (short)f2bf(v1.w);
        ((bf16x8*)inb)[i] = p;
    } else {
        // wt [k=1152][f=256] fp32 -> [f=256][k=1152] bf16
        const int t = (b - 8192) * 256 + threadIdx.x;   // 0 .. 36863
        const int f = t / 144, k8 = t % 144;
        bf16x8 p;
        #pragma unroll
        for (int j = 0; j < 8; ++j)
            p[j] = (short)f2bf(wt[(k8 * 8 + j) * Fo + f]);
        ((bf16x8*)wtb)[f * 144 + k8] = p;
    }
}

// ---- main: R11 skeleton + sched_barrier(0)-pinned read/MFMA alternation ----
__global__ __launch_bounds__(256) void conv_mfma(
    const u16* __restrict__ inb,   // bf16 [32][64][64][128]
    const u16* __restrict__ wtb,   // bf16 [256][1152]
    float* __restrict__ out)       // [123008][256] fp32, r=(oh*62+ow)*32+b
{
    __shared__ __align__(16) short As[BM * BK];   // 32 KB, 256B rows, swizzled
    __shared__ __align__(16) short Bs[BM * BK];   // 32 KB, 256B rows, swizzled

    const int tid  = threadIdx.x;
    const int lane = tid & 63;
    const int wv   = tid >> 6;
    const int wr   = wv >> 1, wc = wv & 1;

    // bijective XCD swizzle
    constexpr int q = NWG / 8, rr = NWG % 8;
    const int orig = blockIdx.x;
    const int xcd = orig & 7, idx = orig >> 3;
    const int wgid = (xcd < rr ? xcd * (q + 1) : rr * (q + 1) + (xcd - rr) * q) + idx;

    const int colb = wgid & 1;
    const int rowb = wgid >> 1;
    const int r0   = rowb * BM;
    const int f0g  = colb * 128;

    // ---- DMA staging addresses (identical to R11) ----
    const int lrow4 = lane >> 4;                 // 0..3
    const int chunk = lane & 15;
    int abyte[8], bbyte[8];
    #pragma unroll
    for (int j = 0; j < 8; ++j) {
        const int rl = wv * 32 + j * 4 + lrow4;  // local row 0..127
        const int sw = (chunk ^ (rl & 15)) * 16;
        const int r  = r0 + rl;
        const int bb = r & 31;
        const int pix = r >> 5;
        const int ow = pix % OW, oh = pix / OW;
        abyte[j] = ((bb * Hh + oh) * Ww + ow) * Ci * 2 + sw;
        bbyte[j] = (f0g + rl) * (Ktot * 2) + sw;
    }

    auto stage = [&](int step) {
        const int kh = step / 3, kw = step % 3;
        const int tap = (kh * Ww + kw) * Ci * 2;
        const int bof = step * 256;
        #pragma unroll
        for (int j = 0; j < 8; ++j)
            GLD_LDS((const char*)inb + abyte[j] + tap, &As[(wv * 32 + j * 4) * BK]);
        #pragma unroll
        for (int j = 0; j < 8; ++j)
            GLD_LDS((const char*)wtb + bbyte[j] + bof, &Bs[(wv * 32 + j * 4) * BK]);
    };

    f32x4 acc[4][4];
    #pragma unroll
    for (int m = 0; m < 4; ++m)
        #pragma unroll
        for (int n = 0; n < 4; ++n) acc[m][n] = (f32x4){0.f, 0.f, 0.f, 0.f};

    stage(0);

    const int lrow = lane & 15;
    const int lq   = lane >> 4;

    // fragment read for one K=32 substep: 4 A + 4 B ds_read_b128
    auto readfr = [&](int ks, bf16x8 (&a)[4], bf16x8 (&b)[4]) {
        const int off = ks * 64 + lq * 16;       // byte offset within 256B row
        #pragma unroll
        for (int m = 0; m < 4; ++m) {
            const int row = wr * 64 + m * 16 + lrow;
            a[m] = *(const bf16x8*)((const char*)As + row * 256 + (off ^ ((row & 15) << 4)));
        }
        #pragma unroll
        for (int n = 0; n < 4; ++n) {
            const int frow = wc * 64 + n * 16 + lrow;
            b[n] = *(const bf16x8*)((const char*)Bs + frow * 256 + (off ^ ((frow & 15) << 4)));
        }
    };
    auto mfma16 = [&](const bf16x8 (&a)[4], const bf16x8 (&b)[4]) {
        #pragma unroll
        for (int m = 0; m < 4; ++m)
            #pragma unroll
            for (int n = 0; n < 4; ++n)
                acc[m][n] = __builtin_amdgcn_mfma_f32_16x16x32_bf16(a[m], b[n], acc[m][n], 0, 0, 0);
    };

    for (int step = 0; step < NSTEP; ++step) {
        __syncthreads();   // drains DMA: staged tile ready

        // 2-slot, SB(0)-pinned alternation: nothing crosses the fences, so
        // each read cluster issues between the previous MFMA clusters and the
        // compiler's fine lgkmcnt waits only on the slot being consumed.
        bf16x8 a0[4], b0[4], a1[4], b1[4];
        readfr(0, a0, b0);
        readfr(1, a1, b1);
        SB0;
        mfma16(a0, b0);        // waits lgkmcnt(8): ks0 landed, ks1 in flight
        SB0;
        readfr(2, a0, b0);
        SB0;
        mfma16(a1, b1);        // ks1 (landed during MFMA ks0)
        SB0;
        readfr(3, a1, b1);
        SB0;
        mfma16(a0, b0);        // ks2
        SB0;
        mfma16(a1, b1);        // ks3

        __syncthreads();   // all waves done reading
        if (step + 1 < NSTEP) stage(step + 1);
    }

    // ---- epilogue: relu + store ----
    const int lcol = lane & 15;
    const int lr4  = (lane >> 4) * 4;
    #pragma unroll
    for (int m = 0; m < 4; ++m) {
        #pragma unroll
        for (int n = 0; n < 4; ++n) {
            const int col = f0g + wc * 64 + n * 16 + lcol;
            const int rowbase = r0 + wr * 64 + m * 16 + lr4;
            #pragma unroll
            for (int e = 0; e < 4; ++e) {
                float v = acc[m][n][e];
                out[(long)(rowbase + e) * Fo + col] = v > 0.f ? v : 0.f;
            }
        }
    }
}

// ================== fallback (round-2 proven kernel, no workspace) ==================
__global__ __launch_bounds__(256) void conv_mfma_fb(
    const float* __restrict__ in, const float* __restrict__ wt,
    float* __restrict__ out)
{
    __shared__ __align__(16) short As[128 * 64];
    __shared__ __align__(16) short Bs[128 * 64];
    const int tid  = threadIdx.x;
    const int lane = tid & 63;
    const int wv   = tid >> 6;
    const int wr   = wv >> 1, wc = wv & 1;
    constexpr int q2 = NWG / 8, rr2 = NWG % 8;
    const int orig = blockIdx.x;
    const int xcd = orig & 7, idx = orig >> 3;
    const int wgid = (xcd < rr2 ? xcd * (q2 + 1) : rr2 * (q2 + 1) + (xcd - rr2) * q2) + idx;
    const int colb = wgid & 1;
    const int rowb = wgid >> 1;
    const int r0   = rowb * 128;
    const int f0g  = colb * 128;
    const int ai = tid >> 1;
    const int ah = tid & 1;
    const int r  = r0 + ai;
    const int bb  = r & 31;
    const int pix = r >> 5;
    const int ow  = pix % OW;
    const int oh  = pix / OW;
    const float* abase = in + ((bb * Hh + oh) * Ww + ow) * Ci;
    const int bk = tid & 63;
    const int bf = (tid >> 6) * 32;
    constexpr int FNSTEP = 18;

    auto loadA = [&](int step, float4 (&pa)[8]) {
        const int kb = step >> 1;
        const int c0 = (step & 1) << 6;
        const int kh = kb / 3, kw = kb % 3;
        const float* src = abase + (kh * Ww + kw) * Ci + c0 + ah * 32;
        #pragma unroll
        for (int c = 0; c < 8; ++c) pa[c] = ((const float4*)src)[c];
    };
    auto writeA = [&](const float4 (&pa)[8]) {
        char* dst = (char*)As + ai * 128;
        const int swz = (ai & 7) << 4;
        #pragma unroll
        for (int c = 0; c < 4; ++c) {
            float4 v0 = pa[2 * c], v1 = pa[2 * c + 1];
            bf16x8 pk;
            pk[0] = (short)f2bf(v0.x); pk[1] = (short)f2bf(v0.y);
            pk[2] = (short)f2bf(v0.z); pk[3] = (short)f2bf(v0.w);
            pk[4] = (short)f2bf(v1.x); pk[5] = (short)f2bf(v1.y);
            pk[6] = (short)f2bf(v1.z); pk[7] = (short)f2bf(v1.w);
            *(bf16x8*)(dst + ((ah * 64 + c * 16) ^ swz)) = pk;
        }
    };
    auto loadB = [&](int step, float4 (&pb)[8]) {
        const float* src = wt + (step * 64 + bk) * Fo + f0g + bf;
        #pragma unroll
        for (int c = 0; c < 8; ++c) pb[c] = ((const float4*)src)[c];
    };
    auto writeB = [&](const float4 (&pb)[8]) {
        const int k2 = bk * 2;
        #pragma unroll
        for (int c = 0; c < 8; ++c) {
            float4 v = pb[c];
            const int fl = bf + c * 4;
            *(u16*)((char*)Bs + (fl + 0) * 128 + (k2 ^ (((fl + 0) & 7) << 4))) = f2bf(v.x);
            *(u16*)((char*)Bs + (fl + 1) * 128 + (k2 ^ (((fl + 1) & 7) << 4))) = f2bf(v.y);
            *(u16*)((char*)Bs + (fl + 2) * 128 + (k2 ^ (((fl + 2) & 7) << 4))) = f2bf(v.z);
            *(u16*)((char*)Bs + (fl + 3) * 128 + (k2 ^ (((fl + 3) & 7) << 4))) = f2bf(v.w);
        }
    };

    f32x4 acc[4][4];
    #pragma unroll
    for (int m = 0; m < 4; ++m)
        #pragma unroll
        for (int n = 0; n < 4; ++n) acc[m][n] = (f32x4){0.f, 0.f, 0.f, 0.f};
    {
        float4 pa[8], pb[8];
        loadA(0, pa); loadB(0, pb);
        writeA(pa); writeB(pb);
    }
    __syncthreads();
    const int lrow = tid & 15;
    const int lq   = (tid & 63) >> 4;
    for (int step = 0; step < FNSTEP; ++step) {
        float4 na[8], nb[8];
        if (step + 1 < FNSTEP) { loadA(step + 1, na); loadB(step + 1, nb); }
        #pragma unroll
        for (int ks = 0; ks < 2; ++ks) {
            bf16x8 a[4], b[4];
            const int off = ks * 64 + lq * 16;
            #pragma unroll
            for (int m = 0; m < 4; ++m) {
                const int row = wr * 64 + m * 16 + lrow;
                a[m] = *(const bf16x8*)((const char*)As + row * 128 + (off ^ ((row & 7) << 4)));
            }
            #pragma unroll
            for (int n = 0; n < 4; ++n) {
                const int row = wc * 64 + n * 16 + lrow;
                b[n] = *(const bf16x8*)((const char*)Bs + row * 128 + (off ^ ((row & 7) << 4)));
            }
            #pragma unroll
            for (int m = 0; m < 4; ++m)
                #pragma unroll
                for (int n = 0; n < 4; ++n)
                    acc[m][n] = __builtin_amdgcn_mfma_f32_16x16x32_bf16(a[m], b[n], acc[m][n], 0, 0, 0);
        }
        __syncthreads();
        if (step + 1 < FNSTEP) { writeA(na); writeB(nb); }
        __syncthreads();
    }
    const int lcol = tid & 15;
    const int lr4  = ((tid & 63) >> 4) * 4;
    #pragma unroll
    for (int m = 0; m < 4; ++m) {
        #pragma unroll
        for (int n = 0; n < 4; ++n) {
            const int col = f0g + wc * 64 + n * 16 + lcol;
            const int rowbase = r0 + wr * 64 + m * 16 + lr4;
            #pragma unroll
            for (int e = 0; e < 4; ++e) {
                float v = acc[m][n][e];
                out[(rowbase + e) * Fo + col] = v > 0.f ? v : 0.f;
            }
        }
    }
}

extern "C" void kernel_launch(void* const* d_in, const int* in_sizes, int n_in,
                              void* d_out, int out_size, void* d_ws, size_t ws_size,
                              hipStream_t stream) {
    const float* in  = (const float*)d_in[0];
    const float* wt  = (const float*)d_in[1];
    float* out = (float*)d_out;
    if (ws_size >= WS_NEED) {
        u16* inb = (u16*)d_ws;
        u16* wtb = (u16*)((char*)d_ws + WS_WT_OFF);
        cvt_all<<<dim3(8336), dim3(256), 0, stream>>>(in, wt, inb, wtb);
        conv_mfma<<<dim3(NWG), dim3(256), 0, stream>>>(inb, wtb, out);
    } else {
        conv_mfma_fb<<<dim3(NWG), dim3(256), 0, stream>>>(in, wt, out);
    }
}